// Round 19
// baseline (53.971 us; speedup 1.0000x reference)
//
#include <hip/hip_runtime.h>
#include <cfloat>

#define TOKENS 16384   // B*N
#define DDIM   2048
#define NEXP   128
#define KTOP   8
#define MB     64      // tokens per block
#define CH     128     // k elements per chunk
#define NCH    (DDIM / CH)   // 16
#define NTHR   512     // 8 waves/block, grid 256 -> 1 block/CU

typedef float    f32x4 __attribute__((ext_vector_type(4)));
typedef _Float16 f16x8 __attribute__((ext_vector_type(8)));

// W fragment tables in d_ws (rebuilt each launch); layout unchanged from
// R10-R18 (64k-granular): linear index (eb*64 + c*4 + ks)*64 + lane for
// CH=128 chunk c (0..15), ks (0..3).
#define WFRAG_N (8 * 64 * 64)   // 32768 uint4 per table (512 KB)

__device__ __forceinline__ unsigned short f16bits(float f) {
    _Float16 h = (_Float16)f;                      // RNE
    return __builtin_bit_cast(unsigned short, h);
}
__device__ __forceinline__ float f16tof(unsigned short u) {
    return (float)__builtin_bit_cast(_Float16, u); // exact
}

__global__ __launch_bounds__(256, 1) void wfrag_kernel(
    const float* __restrict__ W, uint4* __restrict__ wf)
{
    int id   = blockIdx.x * 256 + threadIdx.x;   // 0..32767
    int lane = id & 63;
    int ks   = (id >> 6) & 1;
    int c    = (id >> 7) & 31;
    int eb   = id >> 12;
    int e    = eb * 16 + (lane & 15);
    int k0   = c * 64 + ks * 32 + (lane >> 4) * 8;
    const float4* src = (const float4*)(W + (size_t)e * DDIM + k0);
    float4 a = src[0], bq = src[1];      // vectorized (was 8 scalar loads)
    float v[8] = {a.x, a.y, a.z, a.w, bq.x, bq.y, bq.z, bq.w};
    unsigned hw[4], mw[4];
#pragma unroll
    for (int p = 0; p < 4; ++p) {
        unsigned short h0 = f16bits(v[2 * p]), h1 = f16bits(v[2 * p + 1]);
        unsigned short m0 = f16bits((v[2 * p]     - f16tof(h0)) * 4096.0f);
        unsigned short m1 = f16bits((v[2 * p + 1] - f16tof(h1)) * 4096.0f);
        hw[p] = (unsigned)h0 | ((unsigned)h1 << 16);
        mw[p] = (unsigned)m0 | ((unsigned)m1 << 16);
    }
    wf[id]           = make_uint4(hw[0], hw[1], hw[2], hw[3]);
    wf[WFRAG_N + id] = make_uint4(mw[0], mw[1], mw[2], mw[3]);
}

// branchless sorted-insert into descending top-8 list.
// strict '>' => ties keep the earlier (lower) index, matching jax.lax.top_k.
__device__ __forceinline__ void insert8(float (&vals)[8], int (&idxs)[8], float v, int e) {
    bool c[8];
#pragma unroll
    for (int p = 0; p < 8; ++p) c[p] = v > vals[p];
#pragma unroll
    for (int p = 7; p >= 1; --p) {
        vals[p] = c[p] ? (c[p - 1] ? vals[p - 1] : v) : vals[p];
        idxs[p] = c[p] ? (c[p - 1] ? idxs[p - 1] : e) : idxs[p];
    }
    vals[0] = c[0] ? v : vals[0];
    idxs[0] = c[0] ? e : idxs[0];
}

// fp16-split MFMA router = R17 structure with CH 64 -> 128 (16 chunks, half
// the barriers / per-iteration overhead; R18 showed x-depth saturated, so the
// residual is per-chunk serial cost ~4000cy vs ~2000cy pipe work). x pipeline
// 2-deep at CH128 = same 16KB/CU in flight as R17's 4-deep. Per-logit k-order
// (CH128 c, ks0..3 == CH64 2c,2c+1) identical -> bit-identical logits.
__device__ __forceinline__ void chunk_barrier() {
    asm volatile("s_waitcnt lgkmcnt(0)" ::: "memory");
    __builtin_amdgcn_sched_barrier(0);
    __builtin_amdgcn_s_barrier();
    __builtin_amdgcn_sched_barrier(0);
}

__global__ __launch_bounds__(NTHR, 1) void router_kernel(
    const float* __restrict__ x, const uint4* __restrict__ wf,
    const float* __restrict__ b, float* __restrict__ out_gates,
    float* __restrict__ out_idx)
{
    // GEMM phase: xh bufs @0,16384; xm bufs @32768,49152 (64 KB)
    // Epilogue overlay: lg [64][132] f32 @0 (33792);
    //   plv [256][stride 9] @33792 (9216); pli @43008 (9216)
    __shared__ __align__(16) char smem[65536];
    float* lg  = (float*)smem;
    float* plv = (float*)(smem + 33792);
    int*   pli = (int*)(smem + 43008);

    const int tid  = threadIdx.x;
    const int lane = tid & 63;
    const int wid  = tid >> 6;           // wave 0..7 -> expert-block eb = wid
    const int tok0 = blockIdx.x * MB;

    const uint4* WFH = wf;
    const uint4* WFM = wf + WFRAG_N;

    f32x4 acc1[4], acc2[4];              // [mf] -> tokens 16*mf..16*mf+15
#pragma unroll
    for (int mf = 0; mf < 4; ++mf) {
        acc1[mf] = (f32x4){0.f, 0.f, 0.f, 0.f};
        acc2[mf] = (f32x4){0.f, 0.f, 0.f, 0.f};
    }

    const float4* x4 = (const float4*)x;
    // x staging: 512 threads stage 64 rows x 32 float4-cols (2 rows x 2 cols)
    const int xr0 = tid >> 4, xr1 = 32 + (tid >> 4), xq = tid & 15;
    const size_t xoff0 = (size_t)(tok0 + xr0) * (DDIM / 4) + xq;
    const size_t xoff1 = (size_t)(tok0 + xr1) * (DDIM / 4) + xq;

    // 2-deep x pipeline; S[r*2+cc] = row r, float4-col xq+16*cc of the chunk
    float4 S0[4], S1[4];
    uint4  wA[8], wB[8];                 // [ks]=wh, [4+ks]=wm (ks 0..3)

    auto loadX = [&](int c, float4 (&S)[4]) {
        const size_t o = (size_t)c * 32;
        S[0] = x4[xoff0 + o];  S[1] = x4[xoff0 + o + 16];
        S[2] = x4[xoff1 + o];  S[3] = x4[xoff1 + o + 16];
    };
    auto loadW = [&](int c, uint4 (&wreg)[8]) {
#pragma unroll
        for (int ks = 0; ks < 4; ++ks) {
            int idx = (wid * 64 + c * 4 + ks) * 64 + lane;
            wreg[ks]     = WFH[idx];
            wreg[4 + ks] = WFM[idx];
        }
    };
    // swizzle: row stride 256B, 16 slots of 16B, slot ^= row&15
    auto convertX = [&](const float4 (&S)[4], char* hbase) {
#pragma unroll
        for (int r = 0; r < 2; ++r)
#pragma unroll
            for (int cc = 0; cc < 2; ++cc) {
                const float4 v = S[r * 2 + cc];
                const int row = r ? xr1 : xr0;
                const int q   = xq + 16 * cc;           // float4-col 0..31
                unsigned short h0 = f16bits(v.x), h1 = f16bits(v.y);
                unsigned short h2 = f16bits(v.z), h3 = f16bits(v.w);
                unsigned short m0 = f16bits((v.x - f16tof(h0)) * 4096.0f);
                unsigned short m1 = f16bits((v.y - f16tof(h1)) * 4096.0f);
                unsigned short m2 = f16bits((v.z - f16tof(h2)) * 4096.0f);
                unsigned short m3 = f16bits((v.w - f16tof(h3)) * 4096.0f);
                uint2 hv = make_uint2((unsigned)h0 | ((unsigned)h1 << 16),
                                      (unsigned)h2 | ((unsigned)h3 << 16));
                uint2 mv = make_uint2((unsigned)m0 | ((unsigned)m1 << 16),
                                      (unsigned)m2 | ((unsigned)m3 << 16));
                const int byteoff = row * 256 +
                    (((q >> 1) ^ (row & 15)) << 4) + (q & 1) * 8;
                *(uint2*)(hbase + byteoff)         = hv;
                *(uint2*)(hbase + 32768 + byteoff) = mv;
            }
    };

    // step chunk c: issue x(c+2), W(c+1); 16 ds_read_b128 + 48 MFMAs;
    // convert x(c+1) -> other buffer; one barrier.
    auto step = [&](int c, float4 (&Sload)[4], float4 (&Scvt)[4],
                    uint4 (&wCur)[8], uint4 (&wNext)[8],
                    char* bufCur, char* bufNext) {
        if (c + 2 < NCH) loadX(c + 2, Sload);
        if (c + 1 < NCH) loadW(c + 1, wNext);

#pragma unroll
        for (int ks = 0; ks < 4; ++ks) {
            f16x8 ah[4], am[4];
#pragma unroll
            for (int mf = 0; mf < 4; ++mf) {
                int row = 16 * mf + (lane & 15);
                int s16 = (ks * 4 + (lane >> 4)) ^ (row & 15);
                int byteoff = row * 256 + (s16 << 4);
                ah[mf] = *(const f16x8*)(bufCur + byteoff);
                am[mf] = *(const f16x8*)(bufCur + 32768 + byteoff);
            }
            f16x8 wh = __builtin_bit_cast(f16x8, wCur[ks]);
            f16x8 wm = __builtin_bit_cast(f16x8, wCur[4 + ks]);
#pragma unroll
            for (int mf = 0; mf < 4; ++mf) {
                acc1[mf] = __builtin_amdgcn_mfma_f32_16x16x32_f16(
                    ah[mf], wh, acc1[mf], 0, 0, 0);
                acc2[mf] = __builtin_amdgcn_mfma_f32_16x16x32_f16(
                    ah[mf], wm, acc2[mf], 0, 0, 0);
                acc2[mf] = __builtin_amdgcn_mfma_f32_16x16x32_f16(
                    am[mf], wh, acc2[mf], 0, 0, 0);
            }
        }

        if (c + 1 < NCH) convertX(Scvt, bufNext);
        chunk_barrier();
    };

    // ---- prologue ----
    loadX(0, S0);
    loadX(1, S1);
    loadW(0, wA);
    convertX(S0, smem);
    chunk_barrier();

    char* buf0 = smem;
    char* buf1 = smem + 16384;
    for (int cc = 0; cc < NCH; cc += 2) {
        step(cc,     S0, S1, wA, wB, buf0, buf1);
        step(cc + 1, S1, S0, wB, wA, buf1, buf0);
    }

    // ---- epilogue: logits -> LDS (C/D: col=lane&15 -> expert,
    // row=(lane>>4)*4+reg -> token) ----
    const float bb = b[wid * 16 + (lane & 15)];
#pragma unroll
    for (int mf = 0; mf < 4; ++mf)
#pragma unroll
        for (int r = 0; r < 4; ++r) {
            int t = 16 * mf + (lane >> 4) * 4 + r;
            int e = wid * 16 + (lane & 15);
            lg[t * 132 + e] =
                fmaf(acc2[mf][r], 0.000244140625f, acc1[mf][r]) + bb;
        }
    __syncthreads();

    // ---- partial top-8: 4 threads per token, 32 experts each ----
    if (tid < 256) {
        int tt = tid >> 2, p = tid & 3;
        float vals[8]; int idxs[8];
#pragma unroll
        for (int k = 0; k < 8; ++k) { vals[k] = -FLT_MAX; idxs[k] = 0; }
        const float* row = &lg[tt * 132 + p * 32];
        for (int q = 0; q < 32; ++q)
            insert8(vals, idxs, row[q], p * 32 + q);
#pragma unroll
        for (int k = 0; k < 8; ++k) {
            plv[tid * 9 + k] = vals[k];   // stride 9: conflict-free merge
            pli[tid * 9 + k] = idxs[k];
        }
    }
    __syncthreads();

    // ---- merge + softmax + index output (1 thread per token) ----
    float g[8]; int fidx[8];
    const bool active = (tid < MB);
    if (active) {
        float vals[8]; int idxs[8];
#pragma unroll
        for (int k = 0; k < 8; ++k) { vals[k] = -FLT_MAX; idxs[k] = 0; }
        for (int p = 0; p < 4; ++p) {
#pragma unroll
            for (int k = 0; k < 8; ++k)
                insert8(vals, idxs, plv[(tid * 4 + p) * 9 + k], pli[(tid * 4 + p) * 9 + k]);
        }
        float mx = vals[0];
        float s = 0.0f;
#pragma unroll
        for (int k = 0; k < 8; ++k) { g[k] = __expf(vals[k] - mx); s += g[k]; }
        float inv = 1.0f / s;
#pragma unroll
        for (int k = 0; k < 8; ++k) { g[k] *= inv; fidx[k] = idxs[k]; }
        // indices written as float values (whole out buffer is read back as f32)
#pragma unroll
        for (int k = 0; k < 8; ++k)
            out_idx[(size_t)(tok0 + tid) * KTOP + k] = (float)idxs[k];
    }
    // zero dense gate rows (merge no longer reads lg)
    for (int f = tid; f < MB * 132; f += NTHR) lg[f] = 0.0f;
    __syncthreads();

    if (active) {
#pragma unroll
        for (int k = 0; k < 8; ++k) lg[tid * 132 + fidx[k]] = g[k];
    }
    __syncthreads();

    // ---- coalesced dense copy-out ----
    for (int f = tid; f < MB * (NEXP / 4); f += NTHR) {
        int m = f >> 5, e4 = f & 31;
        float4 v = *(const float4*)&lg[m * 132 + e4 * 4];
        ((float4*)out_gates)[(size_t)(tok0 + m) * (NEXP / 4) + e4] = v;
    }
}

extern "C" void kernel_launch(void* const* d_in, const int* in_sizes, int n_in,
                              void* d_out, int out_size, void* d_ws, size_t ws_size,
                              hipStream_t stream) {
    const float* x = (const float*)d_in[0];   // [B,N,D] f32
    const float* W = (const float*)d_in[1];   // [E,D]   f32
    const float* b = (const float*)d_in[2];   // [E]     f32

    float* out_gates = (float*)d_out;                       // [B,N,E] f32
    float* out_idx   = out_gates + (size_t)TOKENS * NEXP;   // [B,N,K] as f32

    uint4* wf = (uint4*)d_ws;   // 1 MB: W fp16 h/m fragment tables

    wfrag_kernel<<<dim3(WFRAG_N / 256), dim3(256), 0, stream>>>(W, wf);
    router_kernel<<<dim3(TOKENS / MB), dim3(NTHR), 0, stream>>>(x, wf, b, out_gates, out_idx);
}